// Round 1
// baseline (457.753 us; speedup 1.0000x reference)
//
#include <hip/hip_runtime.h>
#include <stdint.h>

// KohonenMap: x [65536,64] f32, nodes [4096,64] f32
// out = concat( node_repr [65536,64] f32 , winning_indices [65536] as f32 )
//
// Plan: scores s_k = n2[k] - 2*(x . n_k)  (x^2 row-constant, irrelevant to argmin)
// Phase 1: split-bf16 MFMA (hi/lo, 4 products) 32x32x16, fused per-row argmin + top-2 margin.
// Phase 2: rows with margin <= TAU re-solved exactly in f64 (true argmin, first-index ties).
//
// ws layout (needs ~1.4 MiB):
//   [0]       int   refine_cnt
//   [64]      int   refine_list[65536]          (256 KiB)
//   [262208]  float n2f[4096]                   (16 KiB)
//   [278592]  double n2d[4096]                  (32 KiB)
//   [311360]  u16   bfrag[128][4][2][512]       (1 MiB)  fragment-order bf16 nodes hi/lo

typedef unsigned short u16;
typedef __bf16 bf16x8 __attribute__((ext_vector_type(8)));
typedef unsigned short u16x8 __attribute__((ext_vector_type(8)));
typedef float f32x16 __attribute__((ext_vector_type(16)));

#define B_ROWS 65536
#define K_NODES 4096
#define DIM 64
#define NTILES 128
#define TAU 0.05f

#define OFF_LIST 64
#define OFF_N2F  262208
#define OFF_N2D  278592
#define OFF_BFRAG 311360

__device__ __forceinline__ u16 bf16_rne(float f, float& back) {
    uint32_t u = __float_as_uint(f);
    uint32_t r = u + 0x7FFFu + ((u >> 16) & 1u);
    u16 h = (u16)(r >> 16);
    back = __uint_as_float(((uint32_t)h) << 16);
    return h;
}

// ---------------- prep: fragment-order bf16 hi/lo of nodes -------------------
__global__ __launch_bounds__(256) void prep_bfrag(const float* __restrict__ nodes,
                                                  u16* __restrict__ bfrag) {
    int gid = blockIdx.x * 256 + threadIdx.x;   // 0 .. NTILES*64-1
    int t = gid >> 6, l = gid & 63;
    const float* row = nodes + (size_t)(t * 32 + (l & 31)) * DIM + ((l >> 5) * 8);
    #pragma unroll
    for (int c = 0; c < 4; ++c) {
        u16x8 hv, lv;
        #pragma unroll
        for (int j = 0; j < 8; ++j) {
            float f = row[c * 16 + j];
            float hf;
            u16 hb = bf16_rne(f, hf);
            float dummy;
            u16 lb = bf16_rne(f - hf, dummy);
            hv[j] = hb; lv[j] = lb;
        }
        int base = ((t * 4 + c) * 2) * 512 + l * 8;  // u16 index
        *(u16x8*)(bfrag + base)       = hv;
        *(u16x8*)(bfrag + base + 512) = lv;
    }
}

// ---------------- prep: n2 in f32 and f64 ------------------------------------
__global__ __launch_bounds__(256) void prep_n2(const float* __restrict__ nodes,
                                               float* __restrict__ n2f,
                                               double* __restrict__ n2d) {
    int k = blockIdx.x * 256 + threadIdx.x;
    if (k < K_NODES) {
        const float* r = nodes + (size_t)k * DIM;
        double s = 0.0;
        #pragma unroll
        for (int d = 0; d < DIM; ++d) { double v = (double)r[d]; s += v * v; }
        n2d[k] = s;
        n2f[k] = (float)s;
    }
}

// ---------------- phase 1: MFMA scores + fused argmin ------------------------
__global__ __launch_bounds__(256) void phase1(const float* __restrict__ x,
                                              const float* __restrict__ nodes,
                                              const u16* __restrict__ bfrag_g,
                                              const float* __restrict__ n2f,
                                              float* __restrict__ out,
                                              int* __restrict__ ref_cnt,
                                              int* __restrict__ ref_list) {
    __shared__ __align__(16) u16 sb[32768];   // 64 KiB: 8 ntiles staged
    const int tid  = threadIdx.x;
    const int lane = tid & 63;
    const int w    = tid >> 6;            // wave 0..3
    const int col  = lane & 31;
    const int lh   = lane >> 5;           // lane half
    const int row0 = blockIdx.x * 128 + w * 32;
    const int r    = row0 + col;

    // A fragments: x row r, split hi/lo in registers. d = lh*8 + c*16 + j
    bf16x8 ah[4], al[4];
    {
        const float* xp = x + (size_t)r * DIM + lh * 8;
        #pragma unroll
        for (int c = 0; c < 4; ++c) {
            u16x8 hv, lv;
            #pragma unroll
            for (int j = 0; j < 8; ++j) {
                float f = xp[c * 16 + j];
                float hf;
                u16 hb = bf16_rne(f, hf);
                float dummy;
                u16 lb = bf16_rne(f - hf, dummy);
                hv[j] = hb; lv[j] = lb;
            }
            union { u16x8 u; bf16x8 b; } cvh, cvl;
            cvh.u = hv; cvl.u = lv;
            ah[c] = cvh.b; al[c] = cvl.b;
        }
    }

    float b1[16], v2[16];
    int   bi[16];
    #pragma unroll
    for (int q = 0; q < 16; ++q) { b1[q] = 3.4e38f; v2[q] = 3.4e38f; bi[q] = 0; }

    const int4* gsrc = (const int4*)bfrag_g;
    for (int s0 = 0; s0 < 16; ++s0) {
        __syncthreads();
        {   // stage 64 KiB (reg-staged copy)
            const int4* g = gsrc + s0 * 4096;
            int4* d = (int4*)sb;
            #pragma unroll 4
            for (int i = 0; i < 16; ++i) d[i * 256 + tid] = g[i * 256 + tid];
        }
        __syncthreads();
        for (int nt = 0; nt < 8; ++nt) {
            const int node0 = s0 * 256 + nt * 32;
            const float n2v = n2f[node0 + col];
            f32x16 acc;
            #pragma unroll
            for (int q = 0; q < 16; ++q) acc[q] = 0.f;
            #pragma unroll
            for (int c = 0; c < 4; ++c) {
                const bf16x8 bh = *(const bf16x8*)(sb + ((nt * 4 + c) * 2 + 0) * 512 + lane * 8);
                const bf16x8 bl = *(const bf16x8*)(sb + ((nt * 4 + c) * 2 + 1) * 512 + lane * 8);
                acc = __builtin_amdgcn_mfma_f32_32x32x16_bf16(ah[c], bh, acc, 0, 0, 0);
                acc = __builtin_amdgcn_mfma_f32_32x32x16_bf16(al[c], bh, acc, 0, 0, 0);
                acc = __builtin_amdgcn_mfma_f32_32x32x16_bf16(ah[c], bl, acc, 0, 0, 0);
                acc = __builtin_amdgcn_mfma_f32_32x32x16_bf16(al[c], bl, acc, 0, 0, 0);
            }
            #pragma unroll
            for (int q = 0; q < 16; ++q) {
                float s = fmaf(-2.f, acc[q], n2v);
                bool lt = s < b1[q];
                v2[q] = fminf(v2[q], lt ? b1[q] : s);
                b1[q] = lt ? s : b1[q];
                bi[q] = lt ? node0 : bi[q];
            }
        }
    }

    // materialize global index (col is this lane's node-within-tile)
    int gi[16];
    #pragma unroll
    for (int q = 0; q < 16; ++q) gi[q] = bi[q] + col;

    // reduce (b1, gi, v2) across the 32 cols (lanes within each half)
    #pragma unroll
    for (int off = 1; off < 32; off <<= 1) {
        #pragma unroll
        for (int q = 0; q < 16; ++q) {
            float ov  = __shfl_xor(b1[q], off, 64);
            float ov2 = __shfl_xor(v2[q], off, 64);
            int   og  = __shfl_xor(gi[q], off, 64);
            float hi2 = fmaxf(b1[q], ov);
            v2[q] = fminf(fminf(v2[q], ov2), hi2);
            bool take = (ov < b1[q]) || (ov == b1[q] && og < gi[q]);
            b1[q] = take ? ov : b1[q];
            gi[q] = take ? og : gi[q];
        }
    }

    __syncthreads();                 // done reading sb; reuse as winner table
    int* s_win = (int*)sb;
    if (col == 0) {                  // lanes 0 and 32 of each wave
        #pragma unroll
        for (int q = 0; q < 16; ++q) {
            int rloc = (q & 3) + 8 * (q >> 2) + 4 * lh;   // 0..31 (C/D layout m74/m101)
            int grow = row0 + rloc;
            s_win[w * 32 + rloc] = gi[q];
            out[(size_t)B_ROWS * DIM + grow] = (float)gi[q];
            if (v2[q] - b1[q] <= TAU) {
                int slot = atomicAdd(ref_cnt, 1);
                ref_list[slot] = grow;
            }
        }
    }
    __syncthreads();
    // cooperative gather of node_repr
    const int base_row = blockIdx.x * 128;
    for (int i = tid; i < 128 * 16; i += 256) {
        int rr = i >> 4, cc = i & 15;
        int wn = s_win[rr];
        float4 v = *(const float4*)(nodes + (size_t)wn * DIM + cc * 4);
        *(float4*)(out + (size_t)(base_row + rr) * DIM + cc * 4) = v;
    }
}

// ---------------- phase 2: exact f64 re-solve for near-tie rows --------------
__global__ __launch_bounds__(256) void phase2(const float* __restrict__ x,
                                              const float* __restrict__ nodes,
                                              const double* __restrict__ n2d,
                                              const int* __restrict__ ref_cnt,
                                              const int* __restrict__ ref_list,
                                              float* __restrict__ out) {
    __shared__ double xs[DIM];
    __shared__ double sval[256];
    __shared__ int    sidx[256];
    const int cnt = *ref_cnt;
    for (int li = blockIdx.x; li < cnt; li += gridDim.x) {
        const int row = ref_list[li];
        __syncthreads();
        if (threadIdx.x < DIM) xs[threadIdx.x] = (double)x[(size_t)row * DIM + threadIdx.x];
        __syncthreads();
        double best = 1e300; int bidx = K_NODES;
        for (int k = threadIdx.x; k < K_NODES; k += 256) {
            const float* np = nodes + (size_t)k * DIM;
            double dot = 0.0;
            #pragma unroll
            for (int d = 0; d < DIM; ++d) dot += xs[d] * (double)np[d];
            double s = n2d[k] - 2.0 * dot;
            if (s < best) { best = s; bidx = k; }
        }
        sval[threadIdx.x] = best; sidx[threadIdx.x] = bidx;
        __syncthreads();
        for (int stride = 128; stride > 0; stride >>= 1) {
            if (threadIdx.x < (unsigned)stride) {
                double ov = sval[threadIdx.x + stride];
                int    oi = sidx[threadIdx.x + stride];
                if (ov < sval[threadIdx.x] ||
                    (ov == sval[threadIdx.x] && oi < sidx[threadIdx.x])) {
                    sval[threadIdx.x] = ov; sidx[threadIdx.x] = oi;
                }
            }
            __syncthreads();
        }
        const int wn = sidx[0];
        if (threadIdx.x == 0) out[(size_t)B_ROWS * DIM + row] = (float)wn;
        if (threadIdx.x < 16) {
            float4 v = *(const float4*)(nodes + (size_t)wn * DIM + threadIdx.x * 4);
            *(float4*)(out + (size_t)row * DIM + threadIdx.x * 4) = v;
        }
        __syncthreads();
    }
}

extern "C" void kernel_launch(void* const* d_in, const int* in_sizes, int n_in,
                              void* d_out, int out_size, void* d_ws, size_t ws_size,
                              hipStream_t stream) {
    const float* x     = (const float*)d_in[0];
    const float* nodes = (const float*)d_in[1];
    float* out = (float*)d_out;
    char*  ws  = (char*)d_ws;

    int*    ref_cnt  = (int*)ws;
    int*    ref_list = (int*)(ws + OFF_LIST);
    float*  n2f      = (float*)(ws + OFF_N2F);
    double* n2d      = (double*)(ws + OFF_N2D);
    u16*    bfrag    = (u16*)(ws + OFF_BFRAG);

    hipMemsetAsync(ref_cnt, 0, 4, stream);
    prep_bfrag<<<NTILES * 64 / 256, 256, 0, stream>>>(nodes, bfrag);
    prep_n2<<<K_NODES / 256, 256, 0, stream>>>(nodes, n2f, n2d);
    phase1<<<B_ROWS / 128, 256, 0, stream>>>(x, nodes, bfrag, n2f, out, ref_cnt, ref_list);
    phase2<<<128, 256, 0, stream>>>(x, nodes, n2d, ref_cnt, ref_list, out);
}

// Round 2
// 225.188 us; speedup vs baseline: 2.0328x; 2.0328x over previous
//
#include <hip/hip_runtime.h>
#include <stdint.h>

// KohonenMap: x [65536,64] f32, nodes [4096,64] f32
// out = concat( node_repr [65536,64] f32 , winning_indices [65536] as f32 )
//
// s_k = n2[k] - 2*(x . n_k)  (x^2 row-constant, irrelevant to argmin)
// Phase 1: split-bf16 MFMA (3 products hh+lh+hl; ll dropped, err ~1e-3),
//          32x32x16, fused per-row top-2 argmin, double-buffered LDS stages
//          via global_load_lds, 8 waves/block, 256 rows/block.
// Phase 2: rows with top-2 margin <= TAU re-solved exactly in f64.
//
// ws layout:
//   [0]       int   refine_cnt
//   [64]      int   refine_list[65536]          (256 KiB)
//   [262208]  float n2f[4096]                   (16 KiB)
//   [278592]  double n2d[4096]                  (32 KiB)
//   [311360]  u16   bfrag[128][4][2][512]       (1 MiB)  fragment-order bf16 nodes hi/lo

typedef unsigned short u16;
typedef __bf16 bf16x8 __attribute__((ext_vector_type(8)));
typedef unsigned short u16x8 __attribute__((ext_vector_type(8)));
typedef float f32x16 __attribute__((ext_vector_type(16)));

#define B_ROWS 65536
#define K_NODES 4096
#define DIM 64
#define NTILES 128
#define TAU 0.03f

#define BM 256            // rows per phase1 block
#define SN 128            // nodes per stage (4 ntiles, 32 KiB)
#define NSTAGES 32

#define OFF_LIST 64
#define OFF_N2F  262208
#define OFF_N2D  278592
#define OFF_BFRAG 311360

#define GLOBAL_AS __attribute__((address_space(1)))
#define LDS_AS    __attribute__((address_space(3)))

__device__ __forceinline__ u16 bf16_rne(float f, float& back) {
    uint32_t u = __float_as_uint(f);
    uint32_t r = u + 0x7FFFu + ((u >> 16) & 1u);
    u16 h = (u16)(r >> 16);
    back = __uint_as_float(((uint32_t)h) << 16);
    return h;
}

// ---------------- prep (merged): bfrag + n2 + ref_cnt reset ------------------
__global__ __launch_bounds__(256) void prep(const float* __restrict__ nodes,
                                            u16* __restrict__ bfrag,
                                            float* __restrict__ n2f,
                                            double* __restrict__ n2d,
                                            int* __restrict__ ref_cnt) {
    if (blockIdx.x == 0 && threadIdx.x == 0) *ref_cnt = 0;
    if (blockIdx.x < 32) {
        int gid = blockIdx.x * 256 + threadIdx.x;   // 0 .. NTILES*64-1
        int t = gid >> 6, l = gid & 63;
        const float* row = nodes + (size_t)(t * 32 + (l & 31)) * DIM + ((l >> 5) * 8);
        #pragma unroll
        for (int c = 0; c < 4; ++c) {
            float4 f0 = *(const float4*)(row + c * 16);
            float4 f1 = *(const float4*)(row + c * 16 + 4);
            float fs[8] = {f0.x, f0.y, f0.z, f0.w, f1.x, f1.y, f1.z, f1.w};
            u16x8 hv, lv;
            #pragma unroll
            for (int j = 0; j < 8; ++j) {
                float hf, dummy;
                u16 hb = bf16_rne(fs[j], hf);
                u16 lb = bf16_rne(fs[j] - hf, dummy);
                hv[j] = hb; lv[j] = lb;
            }
            int base = ((t * 4 + c) * 2) * 512 + l * 8;  // u16 index
            *(u16x8*)(bfrag + base)       = hv;
            *(u16x8*)(bfrag + base + 512) = lv;
        }
    } else {
        int k = (blockIdx.x - 32) * 256 + threadIdx.x;
        if (k < K_NODES) {
            const float* r = nodes + (size_t)k * DIM;
            double s = 0.0;
            #pragma unroll
            for (int d = 0; d < DIM; ++d) { double v = (double)r[d]; s += v * v; }
            n2d[k] = s;
            n2f[k] = (float)s;
        }
    }
}

// ---------------- phase 1: MFMA scores + fused argmin ------------------------
__global__ __launch_bounds__(512, 2) void phase1(const float* __restrict__ x,
                                                 const float* __restrict__ nodes,
                                                 const u16* __restrict__ bfrag_g,
                                                 const float* __restrict__ n2f,
                                                 float* __restrict__ out,
                                                 int* __restrict__ ref_cnt,
                                                 int* __restrict__ ref_list) {
    __shared__ __align__(16) u16 sb[2][16384];   // 2 x 32 KiB double buffer
    const int tid  = threadIdx.x;
    const int lane = tid & 63;
    const int w    = tid >> 6;            // wave 0..7
    const int col  = lane & 31;
    const int lh   = lane >> 5;
    const int row0 = blockIdx.x * BM + w * 32;
    const int r    = row0 + col;

    // A fragments: x row r, split hi/lo in registers. d = lh*8 + c*16 + j
    bf16x8 ah[4], al[4];
    {
        const float* xp = x + (size_t)r * DIM + lh * 8;
        #pragma unroll
        for (int c = 0; c < 4; ++c) {
            float4 f0 = *(const float4*)(xp + c * 16);
            float4 f1 = *(const float4*)(xp + c * 16 + 4);
            float fs[8] = {f0.x, f0.y, f0.z, f0.w, f1.x, f1.y, f1.z, f1.w};
            u16x8 hv, lv;
            #pragma unroll
            for (int j = 0; j < 8; ++j) {
                float hf, dummy;
                u16 hb = bf16_rne(fs[j], hf);
                u16 lb = bf16_rne(fs[j] - hf, dummy);
                hv[j] = hb; lv[j] = lb;
            }
            union { u16x8 u; bf16x8 b; } cvh, cvl;
            cvh.u = hv; cvl.u = lv;
            ah[c] = cvh.b; al[c] = cvl.b;
        }
    }

    float b1[16], v2[16];
    int   bi[16];
    #pragma unroll
    for (int q = 0; q < 16; ++q) { b1[q] = 3.4e38f; v2[q] = 3.4e38f; bi[q] = 0; }

    const char* gbase = (const char*)bfrag_g;

    // prologue: stage 0
    {
        const char* gp = gbase + tid * 16;
        const u16*  lp = &sb[0][0] + tid * 8;
        #pragma unroll
        for (int i = 0; i < 4; ++i)
            __builtin_amdgcn_global_load_lds(
                (const GLOBAL_AS uint32_t*)(gp + i * 8192),
                (LDS_AS uint32_t*)(lp + i * 4096), 16, 0, 0);
    }
    __syncthreads();

    int cur = 0;
    for (int s = 0; s < NSTAGES; ++s) {
        // prefetch stage s+1 into the other buffer
        if (s + 1 < NSTAGES) {
            const char* gp = gbase + (size_t)(s + 1) * 32768 + tid * 16;
            const u16*  lp = &sb[cur ^ 1][0] + tid * 8;
            #pragma unroll
            for (int i = 0; i < 4; ++i)
                __builtin_amdgcn_global_load_lds(
                    (const GLOBAL_AS uint32_t*)(gp + i * 8192),
                    (LDS_AS uint32_t*)(lp + i * 4096), 16, 0, 0);
        }

        // compute on stage s
        const u16* bb = &sb[cur][0];
        float n2v[4];
        #pragma unroll
        for (int nt = 0; nt < 4; ++nt) n2v[nt] = n2f[s * SN + nt * 32 + col];

        f32x16 acc[4];
        #pragma unroll
        for (int nt = 0; nt < 4; ++nt)
            #pragma unroll
            for (int q = 0; q < 16; ++q) acc[nt][q] = 0.f;

        #pragma unroll
        for (int nt = 0; nt < 4; ++nt) {
            #pragma unroll
            for (int c = 0; c < 4; ++c) {
                const bf16x8 bh = *(const bf16x8*)(bb + ((nt * 4 + c) * 2 + 0) * 512 + lane * 8);
                const bf16x8 bl = *(const bf16x8*)(bb + ((nt * 4 + c) * 2 + 1) * 512 + lane * 8);
                acc[nt] = __builtin_amdgcn_mfma_f32_32x32x16_bf16(ah[c], bh, acc[nt], 0, 0, 0);
                acc[nt] = __builtin_amdgcn_mfma_f32_32x32x16_bf16(al[c], bh, acc[nt], 0, 0, 0);
                acc[nt] = __builtin_amdgcn_mfma_f32_32x32x16_bf16(ah[c], bl, acc[nt], 0, 0, 0);
            }
        }

        #pragma unroll
        for (int nt = 0; nt < 4; ++nt) {
            const int node0 = s * SN + nt * 32;
            #pragma unroll
            for (int q = 0; q < 16; ++q) {
                float sc = fmaf(-2.f, acc[nt][q], n2v[nt]);
                v2[q] = fminf(v2[q], fmaxf(sc, b1[q]));   // valid given b1<=v2 invariant
                bool lt = sc < b1[q];
                b1[q] = lt ? sc : b1[q];
                bi[q] = lt ? node0 : bi[q];
            }
        }

        __syncthreads();   // stage s+1 landed (had full compute to cover), buffers safe
        cur ^= 1;
    }

    // materialize global index (col is this lane's node-within-tile)
    int gi[16];
    #pragma unroll
    for (int q = 0; q < 16; ++q) gi[q] = bi[q] + col;

    // reduce (b1, gi, v2) across the 32 cols
    #pragma unroll
    for (int off = 1; off < 32; off <<= 1) {
        #pragma unroll
        for (int q = 0; q < 16; ++q) {
            float ov  = __shfl_xor(b1[q], off, 64);
            float ov2 = __shfl_xor(v2[q], off, 64);
            int   og  = __shfl_xor(gi[q], off, 64);
            float hi2 = fmaxf(b1[q], ov);
            v2[q] = fminf(fminf(v2[q], ov2), hi2);
            bool take = (ov < b1[q]) || (ov == b1[q] && og < gi[q]);
            b1[q] = take ? ov : b1[q];
            gi[q] = take ? og : gi[q];
        }
    }

    int* s_win = (int*)&sb[0][0];
    if (col == 0) {                  // lanes 0 and 32 of each wave
        #pragma unroll
        for (int q = 0; q < 16; ++q) {
            int rloc = (q & 3) + 8 * (q >> 2) + 4 * lh;   // C/D layout (verified r1)
            int grow = row0 + rloc;
            s_win[w * 32 + rloc] = gi[q];
            out[(size_t)B_ROWS * DIM + grow] = (float)gi[q];
            if (v2[q] - b1[q] <= TAU) {
                int slot = atomicAdd(ref_cnt, 1);
                ref_list[slot] = grow;
            }
        }
    }
    __syncthreads();
    // cooperative gather of node_repr
    const int base_row = blockIdx.x * BM;
    for (int i = tid; i < BM * 16; i += 512) {
        int rr = i >> 4, cc = i & 15;
        int wn = s_win[rr];
        float4 v = *(const float4*)(nodes + (size_t)wn * DIM + cc * 4);
        *(float4*)(out + (size_t)(base_row + rr) * DIM + cc * 4) = v;
    }
}

// ---------------- phase 2: exact f64 re-solve for near-tie rows --------------
__global__ __launch_bounds__(256) void phase2(const float* __restrict__ x,
                                              const float* __restrict__ nodes,
                                              const double* __restrict__ n2d,
                                              const int* __restrict__ ref_cnt,
                                              const int* __restrict__ ref_list,
                                              float* __restrict__ out) {
    __shared__ double xs[DIM];
    __shared__ double sval[256];
    __shared__ int    sidx[256];
    const int cnt = *ref_cnt;
    for (int li = blockIdx.x; li < cnt; li += gridDim.x) {
        const int row = ref_list[li];
        __syncthreads();
        if (threadIdx.x < DIM) xs[threadIdx.x] = (double)x[(size_t)row * DIM + threadIdx.x];
        __syncthreads();
        double best = 1e300; int bidx = K_NODES;
        for (int k = threadIdx.x; k < K_NODES; k += 256) {
            const float4* np4 = (const float4*)(nodes + (size_t)k * DIM);
            double d0 = 0.0, d1 = 0.0;
            #pragma unroll
            for (int t = 0; t < 16; t += 2) {
                float4 v0 = np4[t], v1 = np4[t + 1];
                d0 += xs[t*4+0]*(double)v0.x + xs[t*4+1]*(double)v0.y
                    + xs[t*4+2]*(double)v0.z + xs[t*4+3]*(double)v0.w;
                d1 += xs[t*4+4]*(double)v1.x + xs[t*4+5]*(double)v1.y
                    + xs[t*4+6]*(double)v1.z + xs[t*4+7]*(double)v1.w;
            }
            double s = n2d[k] - 2.0 * (d0 + d1);
            if (s < best) { best = s; bidx = k; }
        }
        sval[threadIdx.x] = best; sidx[threadIdx.x] = bidx;
        __syncthreads();
        for (int stride = 128; stride > 0; stride >>= 1) {
            if (threadIdx.x < (unsigned)stride) {
                double ov = sval[threadIdx.x + stride];
                int    oi = sidx[threadIdx.x + stride];
                if (ov < sval[threadIdx.x] ||
                    (ov == sval[threadIdx.x] && oi < sidx[threadIdx.x])) {
                    sval[threadIdx.x] = ov; sidx[threadIdx.x] = oi;
                }
            }
            __syncthreads();
        }
        const int wn = sidx[0];
        if (threadIdx.x == 0) out[(size_t)B_ROWS * DIM + row] = (float)wn;
        if (threadIdx.x < 16) {
            float4 v = *(const float4*)(nodes + (size_t)wn * DIM + threadIdx.x * 4);
            *(float4*)(out + (size_t)row * DIM + threadIdx.x * 4) = v;
        }
        __syncthreads();
    }
}

extern "C" void kernel_launch(void* const* d_in, const int* in_sizes, int n_in,
                              void* d_out, int out_size, void* d_ws, size_t ws_size,
                              hipStream_t stream) {
    const float* x     = (const float*)d_in[0];
    const float* nodes = (const float*)d_in[1];
    float* out = (float*)d_out;
    char*  ws  = (char*)d_ws;

    int*    ref_cnt  = (int*)ws;
    int*    ref_list = (int*)(ws + OFF_LIST);
    float*  n2f      = (float*)(ws + OFF_N2F);
    double* n2d      = (double*)(ws + OFF_N2D);
    u16*    bfrag    = (u16*)(ws + OFF_BFRAG);

    prep<<<48, 256, 0, stream>>>(nodes, bfrag, n2f, n2d, ref_cnt);
    phase1<<<B_ROWS / BM, 512, 0, stream>>>(x, nodes, bfrag, n2f, out, ref_cnt, ref_list);
    phase2<<<256, 256, 0, stream>>>(x, nodes, n2d, ref_cnt, ref_list, out);
}